// Round 1
// baseline (2973.928 us; speedup 1.0000x reference)
//
#include <hip/hip_runtime.h>

// Sinkhorn OT: n=m=4096, d=32, reg=0.1, 100 iterations, uniform marginals.
// K (4096x4096 fp32, 64MB) precomputed into d_ws; 100x (rowdot, coldot)
// kernels; epilogue writes gamma = diag(u) K diag(v).

#define NN 4096
#define MM 4096
#define DD 32
#define N_ITERS 100

static constexpr float INV_REG = 10.0f;           // 1/0.1
static constexpr float A_MARG  = 1.0f / 4096.0f;  // a_i
static constexpr float B_MARG  = 1.0f / 4096.0f;  // b_j

// ---------------------------------------------------------------------------
// K[i][j] = exp(-||x_i - y_j||^2 / reg). Also primes colsum ping-pong bufs:
// csA = 1.0 (so v0 = b/csA = 1/4096), csB = 0.0 (accumulation target, iter 0).
// grid: (MM/256, NN/16), block: 256
// ---------------------------------------------------------------------------
__global__ void compute_K(const float* __restrict__ x, const float* __restrict__ y,
                          float* __restrict__ K, float* __restrict__ csA,
                          float* __restrict__ csB) {
    const int tid = threadIdx.x;
    const int j   = blockIdx.x * 256 + tid;
    const int r0  = blockIdx.y * 16;

    if (blockIdx.y == 0) {  // gridDim.x==16 -> exactly covers 4096 columns
        csA[j] = 1.0f;
        csB[j] = 0.0f;
    }

    // y_j row into registers (8 float4)
    float yv[DD];
    const float4* y4 = (const float4*)(y + (size_t)j * DD);
#pragma unroll
    for (int k = 0; k < DD / 4; ++k) {
        float4 t = y4[k];
        yv[4 * k + 0] = t.x; yv[4 * k + 1] = t.y;
        yv[4 * k + 2] = t.z; yv[4 * k + 3] = t.w;
    }

    // stage 16 x-rows (512 floats) in LDS
    __shared__ float xs[16 * DD];
    if (tid < 256) {
        xs[tid]       = x[(size_t)r0 * DD + tid];
        xs[tid + 256] = x[(size_t)r0 * DD + tid + 256];
    }
    __syncthreads();

#pragma unroll 4
    for (int ii = 0; ii < 16; ++ii) {
        float acc = 0.0f;
#pragma unroll
        for (int k = 0; k < DD; ++k) {
            float d = xs[ii * DD + k] - yv[k];
            acc = fmaf(d, d, acc);
        }
        K[(size_t)(r0 + ii) * MM + j] = __expf(-acc * INV_REG);
    }
}

// ---------------------------------------------------------------------------
// rowsum[i] = sum_j K[i][j] * v[j],  v[j] = b / cs_read[j]
// grid: NN/4 blocks, block 256 (4 waves, one row per wave)
// ---------------------------------------------------------------------------
__global__ void rowdot(const float* __restrict__ K, const float* __restrict__ cs_read,
                       float* __restrict__ rowsum) {
    __shared__ float v_lds[MM];
    const int tid = threadIdx.x;
    for (int j = tid; j < MM; j += 256) v_lds[j] = B_MARG / cs_read[j];
    __syncthreads();

    const int wave = tid >> 6, lane = tid & 63;
    const int i = blockIdx.x * 4 + wave;
    const float4* Krow = (const float4*)(K + (size_t)i * MM);

    float acc = 0.0f;
#pragma unroll
    for (int c = 0; c < MM / 256; ++c) {  // 16 chunks of 256 cols
        float4 kk = Krow[c * 64 + lane];
        int j0 = (c * 64 + lane) * 4;
        acc = fmaf(kk.x, v_lds[j0 + 0], acc);
        acc = fmaf(kk.y, v_lds[j0 + 1], acc);
        acc = fmaf(kk.z, v_lds[j0 + 2], acc);
        acc = fmaf(kk.w, v_lds[j0 + 3], acc);
    }
#pragma unroll
    for (int off = 32; off > 0; off >>= 1) acc += __shfl_down(acc, off, 64);
    if (lane == 0) rowsum[i] = acc;
}

// ---------------------------------------------------------------------------
// cs_write[j] += sum_{i in chunk} K[i][j] * u[i],  u[i] = a / rowsum[i]
// Also zeroes cs_zero (the buffer rowdot just finished reading) for t+1.
// grid: (MM/1024, NN/64) = (4, 64), block 256, 4 cols per thread (float4)
// ---------------------------------------------------------------------------
__global__ void coldot(const float* __restrict__ K, const float* __restrict__ rowsum,
                       float* __restrict__ cs_write, float* __restrict__ cs_zero) {
    __shared__ float u_lds[64];
    const int tid = threadIdx.x;
    const int jb = blockIdx.x, ib = blockIdx.y;
    const int i0 = ib * 64;

    if (tid < 64) u_lds[tid] = A_MARG / rowsum[i0 + tid];

    const int j4 = jb * 1024 + tid * 4;
    if (ib == 0) *(float4*)(cs_zero + j4) = make_float4(0.f, 0.f, 0.f, 0.f);
    __syncthreads();

    float4 acc = make_float4(0.f, 0.f, 0.f, 0.f);
    const float4* Kp = (const float4*)K;
#pragma unroll 8
    for (int ii = 0; ii < 64; ++ii) {
        float u = u_lds[ii];
        float4 kk = Kp[(size_t)(i0 + ii) * (MM / 4) + jb * 256 + tid];
        acc.x = fmaf(kk.x, u, acc.x);
        acc.y = fmaf(kk.y, u, acc.y);
        acc.z = fmaf(kk.z, u, acc.z);
        acc.w = fmaf(kk.w, u, acc.w);
    }
    atomicAdd(cs_write + j4 + 0, acc.x);
    atomicAdd(cs_write + j4 + 1, acc.y);
    atomicAdd(cs_write + j4 + 2, acc.z);
    atomicAdd(cs_write + j4 + 3, acc.w);
}

// ---------------------------------------------------------------------------
// gamma[i][j] = u[i] * K[i][j] * v[j]
// grid: (MM/256, NN/16), block 256
// ---------------------------------------------------------------------------
__global__ void epilogue(const float* __restrict__ K, const float* __restrict__ rowsum,
                         const float* __restrict__ cs, float* __restrict__ out) {
    __shared__ float u_lds[16];
    const int tid = threadIdx.x;
    const int j = blockIdx.x * 256 + tid;
    const int r0 = blockIdx.y * 16;
    if (tid < 16) u_lds[tid] = A_MARG / rowsum[r0 + tid];
    __syncthreads();
    const float v = B_MARG / cs[j];
#pragma unroll 4
    for (int ii = 0; ii < 16; ++ii) {
        size_t idx = (size_t)(r0 + ii) * MM + j;
        out[idx] = u_lds[ii] * K[idx] * v;
    }
}

extern "C" void kernel_launch(void* const* d_in, const int* in_sizes, int n_in,
                              void* d_out, int out_size, void* d_ws, size_t ws_size,
                              hipStream_t stream) {
    const float* x = (const float*)d_in[0];
    const float* y = (const float*)d_in[1];
    float* K      = (float*)d_ws;
    float* rowsum = K + (size_t)NN * MM;
    float* csA    = rowsum + NN;
    float* csB    = csA + MM;
    float* out    = (float*)d_out;

    compute_K<<<dim3(MM / 256, NN / 16), 256, 0, stream>>>(x, y, K, csA, csB);

    for (int t = 0; t < N_ITERS; ++t) {
        float* cs_read  = (t & 1) ? csB : csA;
        float* cs_write = (t & 1) ? csA : csB;
        rowdot<<<NN / 4, 256, 0, stream>>>(K, cs_read, rowsum);
        coldot<<<dim3(MM / 1024, NN / 64), 256, 0, stream>>>(K, rowsum, cs_write, cs_read);
    }

    // after t=99: final u from rowsum, final v in csA (cs_write of t=99)
    epilogue<<<dim3(MM / 256, NN / 16), 256, 0, stream>>>(K, rowsum, csA, out);
}

// Round 2
// 1478.422 us; speedup vs baseline: 2.0116x; 2.0116x over previous
//
#include <hip/hip_runtime.h>
#include <hip/hip_fp16.h>

// Sinkhorn OT: n=m=4096, d=32, reg=0.1, 100 iterations, uniform marginals.
// R2: K and K^T stored fp16 (32MB each) -> iteration matvecs read half the
// bytes of R1, both passes coalesced row-major (no atomics). Each pass writes
// the reciprocal-scaled vector w = marg/dot directly, so the consumer needs
// no divides/LDS. Epilogue recomputes K exactly in fp32 so stored-fp16
// rounding only affects u,v (smoothed by 4096-term sums).

#define NN 4096
#define MM 4096
#define DD 32
#define N_ITERS 100

static constexpr float INV_REG = 10.0f;
static constexpr float A_MARG  = 1.0f / 4096.0f;
static constexpr float B_MARG  = 1.0f / 4096.0f;

// ---------------------------------------------------------------------------
// Kh[i][j] = (half)exp(-||p_i - q_j||^2 / reg), row-major [4096][4096].
// Called twice: (x,y)->Kh and (y,x)->KTh. prime!=0 also sets w_prime[j]=1/4096.
// grid: (4096/256, 4096/16), block 256
// ---------------------------------------------------------------------------
__global__ void compute_K_half(const float* __restrict__ p, const float* __restrict__ q,
                               __half* __restrict__ Kh, float* __restrict__ w_prime,
                               int prime) {
    const int tid = threadIdx.x;
    const int j   = blockIdx.x * 256 + tid;
    const int r0  = blockIdx.y * 16;

    if (prime && blockIdx.y == 0) w_prime[j] = B_MARG;  // v0 = 1/m

    float qv[DD];
    const float4* q4 = (const float4*)(q + (size_t)j * DD);
#pragma unroll
    for (int k = 0; k < DD / 4; ++k) {
        float4 t = q4[k];
        qv[4 * k + 0] = t.x; qv[4 * k + 1] = t.y;
        qv[4 * k + 2] = t.z; qv[4 * k + 3] = t.w;
    }

    __shared__ float ps[16 * DD];
    ps[tid]       = p[(size_t)r0 * DD + tid];
    ps[tid + 256] = p[(size_t)r0 * DD + tid + 256];
    __syncthreads();

#pragma unroll 4
    for (int ii = 0; ii < 16; ++ii) {
        float acc = 0.0f;
#pragma unroll
        for (int k = 0; k < DD; ++k) {
            float d = ps[ii * DD + k] - qv[k];
            acc = fmaf(d, d, acc);
        }
        Kh[(size_t)(r0 + ii) * MM + j] = __float2half(__expf(-acc * INV_REG));
    }
}

// ---------------------------------------------------------------------------
// w_out[i] = marg / sum_j Mat[i][j] * w_in[j]
// One row per wave; 1024 blocks x 4 waves = 4096 rows. K row read as uint4
// (8 halves / 16B per lane), w_in read as float4 from global (L1-resident).
// ---------------------------------------------------------------------------
__global__ void __launch_bounds__(256, 4)
rowpass(const __half* __restrict__ Mat, const float* __restrict__ w_in,
        float* __restrict__ w_out, float marg) {
    const int tid  = threadIdx.x;
    const int lane = tid & 63;
    const int i    = blockIdx.x * 4 + (tid >> 6);

    const uint4*  Mrow = (const uint4*)(Mat + (size_t)i * MM);  // 512 uint4/row
    const float4* W    = (const float4*)w_in;                   // 1024 float4

    float acc = 0.0f;
#pragma unroll
    for (int c = 0; c < 8; ++c) {
        const int g = c * 64 + lane;
        uint4  kk = Mrow[g];
        float4 w0 = W[g * 2 + 0];
        float4 w1 = W[g * 2 + 1];
        float2 f;
        f = __half22float2(*(const __half2*)&kk.x);
        acc = fmaf(f.x, w0.x, acc); acc = fmaf(f.y, w0.y, acc);
        f = __half22float2(*(const __half2*)&kk.y);
        acc = fmaf(f.x, w0.z, acc); acc = fmaf(f.y, w0.w, acc);
        f = __half22float2(*(const __half2*)&kk.z);
        acc = fmaf(f.x, w1.x, acc); acc = fmaf(f.y, w1.y, acc);
        f = __half22float2(*(const __half2*)&kk.w);
        acc = fmaf(f.x, w1.z, acc); acc = fmaf(f.y, w1.w, acc);
    }
#pragma unroll
    for (int off = 32; off > 0; off >>= 1) acc += __shfl_down(acc, off, 64);
    if (lane == 0) w_out[i] = marg / acc;
}

// ---------------------------------------------------------------------------
// gamma[i][j] = u[i] * exp(-||x_i-y_j||^2/reg) * v[j]   (exact fp32 K)
// grid: (16, 256), block 256
// ---------------------------------------------------------------------------
__global__ void epilogue(const float* __restrict__ x, const float* __restrict__ y,
                         const float* __restrict__ u, const float* __restrict__ v,
                         float* __restrict__ out) {
    const int tid = threadIdx.x;
    const int j   = blockIdx.x * 256 + tid;
    const int r0  = blockIdx.y * 16;

    float yv[DD];
    const float4* y4 = (const float4*)(y + (size_t)j * DD);
#pragma unroll
    for (int k = 0; k < DD / 4; ++k) {
        float4 t = y4[k];
        yv[4 * k + 0] = t.x; yv[4 * k + 1] = t.y;
        yv[4 * k + 2] = t.z; yv[4 * k + 3] = t.w;
    }

    __shared__ float xs[16 * DD];
    __shared__ float u_lds[16];
    xs[tid]       = x[(size_t)r0 * DD + tid];
    xs[tid + 256] = x[(size_t)r0 * DD + tid + 256];
    if (tid < 16) u_lds[tid] = u[r0 + tid];
    __syncthreads();

    const float vj = v[j];
#pragma unroll 4
    for (int ii = 0; ii < 16; ++ii) {
        float acc = 0.0f;
#pragma unroll
        for (int k = 0; k < DD; ++k) {
            float d = xs[ii * DD + k] - yv[k];
            acc = fmaf(d, d, acc);
        }
        out[(size_t)(r0 + ii) * MM + j] = u_lds[ii] * __expf(-acc * INV_REG) * vj;
    }
}

extern "C" void kernel_launch(void* const* d_in, const int* in_sizes, int n_in,
                              void* d_out, int out_size, void* d_ws, size_t ws_size,
                              hipStream_t stream) {
    const float* x = (const float*)d_in[0];
    const float* y = (const float*)d_in[1];
    __half* Kh  = (__half*)d_ws;                       // 32 MB
    __half* KTh = Kh + (size_t)NN * MM;                // 32 MB
    float*  w_u = (float*)(KTh + (size_t)NN * MM);     // 16 KB
    float*  w_v = w_u + NN;                            // 16 KB
    float*  out = (float*)d_out;

    compute_K_half<<<dim3(MM / 256, NN / 16), 256, 0, stream>>>(x, y, Kh, w_v, 1);
    compute_K_half<<<dim3(NN / 256, MM / 16), 256, 0, stream>>>(y, x, KTh, w_v, 0);

    for (int t = 0; t < N_ITERS; ++t) {
        rowpass<<<NN / 4, 256, 0, stream>>>(Kh,  w_v, w_u, A_MARG);  // u = a/(K v)
        rowpass<<<MM / 4, 256, 0, stream>>>(KTh, w_u, w_v, B_MARG);  // v = b/(K^T u)
    }

    epilogue<<<dim3(MM / 256, NN / 16), 256, 0, stream>>>(x, y, w_u, w_v, out);
}